// Round 1
// baseline (169.732 us; speedup 1.0000x reference)
//
#include <hip/hip_runtime.h>
#include <math.h>

#define DDIM 640
#define IDIM 640
#define TWO_I 1280
#define KSEL 4
#define NEXP 32
#define NTOK 64
#define EPSV 1e-5f
#define LIMIT 7.0f
#define CHUNK 8

// ws layout (float elements):
//  t_ws   : [64][640]        @ 0        (40960)
//  hact   : [256][640]       @ 40960    (163840)
//  opair  : [256][640]       @ 204800   (163840)
//  ew     : [256]            @ 368640
//  counts : [32] (int)       @ 368896
//  list   : [32][64] (int)   @ 368928
// total ~370976 floats = ~1.49 MB

__global__ void k_rmsnorm(const float* __restrict__ x, const float* __restrict__ nw,
                          float* __restrict__ tws, int* __restrict__ counts) {
    const int t = blockIdx.x;
    const int tid = threadIdx.x;
    if (blockIdx.x == 0 && tid < NEXP) counts[tid] = 0;
    __shared__ float red[256];
    float s = 0.f;
    for (int d = tid; d < DDIM; d += 256) {
        float v = x[d * NTOK + t];
        s += v * v;
    }
    red[tid] = s;
    __syncthreads();
    for (int off = 128; off > 0; off >>= 1) {
        if (tid < off) red[tid] += red[tid + off];
        __syncthreads();
    }
    const float rs = 1.0f / sqrtf(red[0] * (1.0f / DDIM) + EPSV);
    for (int d = tid; d < DDIM; d += 256) {
        tws[t * DDIM + d] = x[d * NTOK + t] * rs * nw[d];
    }
}

__global__ void k_router(const float* __restrict__ tws, const float* __restrict__ gw,
                         const float* __restrict__ gb, float* __restrict__ ew,
                         int* __restrict__ counts, int* __restrict__ list) {
    const int t = blockIdx.x;
    const int lane = threadIdx.x;  // 64 threads, lanes 0..31 active for logits
    __shared__ float lg[NEXP];
    if (lane < NEXP) {
        const float* g = gw + lane * DDIM;
        const float* tr = tws + t * DDIM;
        float acc = 0.f;
        for (int d = 0; d < DDIM; d += 4) {
            acc = fmaf(tr[d], g[d], acc);
            acc = fmaf(tr[d + 1], g[d + 1], acc);
            acc = fmaf(tr[d + 2], g[d + 2], acc);
            acc = fmaf(tr[d + 3], g[d + 3], acc);
        }
        lg[lane] = acc + gb[lane];
    }
    __syncthreads();
    if (lane == 0) {
        float vals[KSEL];
        int idx[KSEL];
        for (int k = 0; k < KSEL; ++k) {
            float best = -1e30f;
            int bi = 0;
            for (int e = 0; e < NEXP; ++e) {
                float v = lg[e];
                if (v > best) { best = v; bi = e; }
            }
            vals[k] = best;
            idx[k] = bi;
            lg[bi] = -1e30f;
        }
        const float m = vals[0];
        float ex[KSEL];
        float se = 0.f;
        for (int k = 0; k < KSEL; ++k) { ex[k] = __expf(vals[k] - m); se += ex[k]; }
        const float inv = 1.0f / se;
        for (int k = 0; k < KSEL; ++k) {
            const int p = t * KSEL + k;
            ew[p] = ex[k] * inv;
            const int slot = atomicAdd(&counts[idx[k]], 1);
            list[idx[k] * NTOK + slot] = p;
        }
    }
}

__global__ __launch_bounds__(64) void k_ffn1(const float* __restrict__ tws,
                                             const float* __restrict__ w1,
                                             const float* __restrict__ b1,
                                             float* __restrict__ hact,
                                             const int* __restrict__ counts,
                                             const int* __restrict__ list) {
    const int e = blockIdx.y;
    const int cnt = counts[e];
    const int c0 = blockIdx.z * CHUNK;
    if (c0 >= cnt) return;
    const int col = blockIdx.x * 64 + threadIdx.x;  // 0..639

    __shared__ float tl[CHUNK][DDIM];
    int pid[CHUNK];
#pragma unroll
    for (int s = 0; s < CHUNK; ++s) {
        int ii = c0 + s;
        ii = (ii < cnt) ? ii : c0;  // pad with first slot of this chunk (identical math)
        pid[s] = list[e * NTOK + ii];
    }
    for (int s = 0; s < CHUNK; ++s) {
        const int tok = pid[s] >> 2;
        for (int d = threadIdx.x; d < DDIM; d += 64) tl[s][d] = tws[tok * DDIM + d];
    }
    __syncthreads();

    const float* w1e = w1 + (size_t)e * DDIM * TWO_I;
    float ag[CHUNK], al[CHUNK];
#pragma unroll
    for (int s = 0; s < CHUNK; ++s) { ag[s] = 0.f; al[s] = 0.f; }

    for (int d = 0; d < DDIM; d += 4) {
        float wg[4], wl[4];
#pragma unroll
        for (int u = 0; u < 4; ++u) {
            wg[u] = w1e[(size_t)(d + u) * TWO_I + col];
            wl[u] = w1e[(size_t)(d + u) * TWO_I + col + IDIM];
        }
#pragma unroll
        for (int s = 0; s < CHUNK; ++s) {
            const float4 tv = *reinterpret_cast<const float4*>(&tl[s][d]);
            ag[s] = fmaf(tv.x, wg[0], ag[s]);
            ag[s] = fmaf(tv.y, wg[1], ag[s]);
            ag[s] = fmaf(tv.z, wg[2], ag[s]);
            ag[s] = fmaf(tv.w, wg[3], ag[s]);
            al[s] = fmaf(tv.x, wl[0], al[s]);
            al[s] = fmaf(tv.y, wl[1], al[s]);
            al[s] = fmaf(tv.z, wl[2], al[s]);
            al[s] = fmaf(tv.w, wl[3], al[s]);
        }
    }

    const float bg = b1[e * TWO_I + col];
    const float bl = b1[e * TWO_I + IDIM + col];
#pragma unroll
    for (int s = 0; s < CHUNK; ++s) {
        float hg = ag[s] + bg;
        hg = fminf(hg, LIMIT);
        float hlin = al[s] + bl;
        hlin = fminf(fmaxf(hlin, -LIMIT), LIMIT);
        const float sig = 1.0f / (1.0f + __expf(-1.702f * hg));
        const float act = hg * sig * (hlin + 1.0f);
        hact[(size_t)pid[s] * IDIM + col] = act;
    }
}

__global__ __launch_bounds__(64) void k_ffn2(const float* __restrict__ hact,
                                             const float* __restrict__ w2,
                                             const float* __restrict__ b2,
                                             const float* __restrict__ ew,
                                             float* __restrict__ opair,
                                             const int* __restrict__ counts,
                                             const int* __restrict__ list) {
    const int e = blockIdx.y;
    const int cnt = counts[e];
    const int c0 = blockIdx.z * CHUNK;
    if (c0 >= cnt) return;
    const int col = blockIdx.x * 64 + threadIdx.x;  // 0..639

    __shared__ float hl[CHUNK][IDIM];
    int pid[CHUNK];
#pragma unroll
    for (int s = 0; s < CHUNK; ++s) {
        int ii = c0 + s;
        ii = (ii < cnt) ? ii : c0;
        pid[s] = list[e * NTOK + ii];
    }
    for (int s = 0; s < CHUNK; ++s) {
        for (int i = threadIdx.x; i < IDIM; i += 64)
            hl[s][i] = hact[(size_t)pid[s] * IDIM + i];
    }
    __syncthreads();

    const float* w2e = w2 + (size_t)e * IDIM * DDIM;
    float acc[CHUNK];
#pragma unroll
    for (int s = 0; s < CHUNK; ++s) acc[s] = 0.f;

    for (int i = 0; i < IDIM; i += 4) {
        float w[4];
#pragma unroll
        for (int u = 0; u < 4; ++u) w[u] = w2e[(size_t)(i + u) * DDIM + col];
#pragma unroll
        for (int s = 0; s < CHUNK; ++s) {
            const float4 hv = *reinterpret_cast<const float4*>(&hl[s][i]);
            acc[s] = fmaf(hv.x, w[0], acc[s]);
            acc[s] = fmaf(hv.y, w[1], acc[s]);
            acc[s] = fmaf(hv.z, w[2], acc[s]);
            acc[s] = fmaf(hv.w, w[3], acc[s]);
        }
    }

    const float bb = b2[e * DDIM + col];
#pragma unroll
    for (int s = 0; s < CHUNK; ++s) {
        opair[(size_t)pid[s] * DDIM + col] = (acc[s] + bb) * ew[pid[s]];
    }
}

__global__ void k_final(const float* __restrict__ x, const float* __restrict__ opair,
                        float* __restrict__ out) {
    const int t = blockIdx.x;
    const int tid = threadIdx.x;
    for (int d = tid; d < DDIM; d += 256) {
        float v = x[d * NTOK + t];
#pragma unroll
        for (int k = 0; k < KSEL; ++k) {
            v += opair[(size_t)(t * KSEL + k) * DDIM + d];
        }
        out[d * NTOK + t] = v;
    }
}

extern "C" void kernel_launch(void* const* d_in, const int* in_sizes, int n_in,
                              void* d_out, int out_size, void* d_ws, size_t ws_size,
                              hipStream_t stream) {
    const float* x  = (const float*)d_in[0];
    const float* nw = (const float*)d_in[1];
    const float* gw = (const float*)d_in[2];
    const float* gb = (const float*)d_in[3];
    const float* w1 = (const float*)d_in[4];
    const float* b1 = (const float*)d_in[5];
    const float* w2 = (const float*)d_in[6];
    const float* b2 = (const float*)d_in[7];
    float* out = (float*)d_out;

    float* ws    = (float*)d_ws;
    float* tws   = ws;             // 40960
    float* hact  = ws + 40960;     // 163840
    float* opair = ws + 204800;    // 163840
    float* ew    = ws + 368640;    // 256
    int* counts  = (int*)(ws + 368896);  // 32
    int* list    = (int*)(ws + 368928);  // 2048

    hipLaunchKernelGGL(k_rmsnorm, dim3(NTOK), dim3(256), 0, stream, x, nw, tws, counts);
    hipLaunchKernelGGL(k_router, dim3(NTOK), dim3(64), 0, stream, tws, gw, gb, ew, counts, list);
    hipLaunchKernelGGL(k_ffn1, dim3(10, NEXP, 8), dim3(64), 0, stream, tws, w1, b1, hact, counts, list);
    hipLaunchKernelGGL(k_ffn2, dim3(10, NEXP, 8), dim3(64), 0, stream, hact, w2, b2, ew, opair, counts, list);
    hipLaunchKernelGGL(k_final, dim3(NTOK), dim3(256), 0, stream, x, opair, out);
}

// Round 2
// 127.156 us; speedup vs baseline: 1.3348x; 1.3348x over previous
//
#include <hip/hip_runtime.h>
#include <math.h>

#define DDIM 640
#define IDIM 640
#define TWO_I 1280
#define KSEL 4
#define NEXP 32
#define NTOK 64
#define NPAIR 256
#define EPSV 1e-5f
#define LIMIT 7.0f
#define CHUNK 8
#define RC 4          // row chunks along the reduction dim
#define RLEN 160      // rows per chunk (640/4)

// ws layout (float elements):
//  tws    : [64][640]            @ 0         (40960)
//  hact   : [256][640]           @ 40960     (163840)
//  hpart  : [4][256][1280]       @ 204800    (1310720)  (ffn1 partials; reused as
//                                                        [4][256][640] for ffn2)
//  ew     : [256]                @ 1515520
//  counts : [32] (int)           @ 1515776
//  list   : [32][64] (int)       @ 1515808
//  pexp   : [256] (int)          @ 1517856
// total ~1518112 floats = ~6.1 MB

__global__ void k_rmsnorm(const float* __restrict__ x, const float* __restrict__ nw,
                          float* __restrict__ tws, int* __restrict__ counts) {
    const int t = blockIdx.x;
    const int tid = threadIdx.x;
    if (blockIdx.x == 0 && tid < NEXP) counts[tid] = 0;
    __shared__ float red[256];
    float s = 0.f;
    for (int d = tid; d < DDIM; d += 256) {
        float v = x[d * NTOK + t];
        s += v * v;
    }
    red[tid] = s;
    __syncthreads();
    for (int off = 128; off > 0; off >>= 1) {
        if (tid < off) red[tid] += red[tid + off];
        __syncthreads();
    }
    const float rs = 1.0f / sqrtf(red[0] * (1.0f / DDIM) + EPSV);
    for (int d = tid; d < DDIM; d += 256) {
        tws[t * DDIM + d] = x[d * NTOK + t] * rs * nw[d];
    }
}

__global__ void k_router(const float* __restrict__ tws, const float* __restrict__ gw,
                         const float* __restrict__ gb, float* __restrict__ ew,
                         int* __restrict__ counts, int* __restrict__ list,
                         int* __restrict__ pexp) {
    const int t = blockIdx.x;
    const int lane = threadIdx.x;
    __shared__ float lg[NEXP];
    if (lane < NEXP) {
        const float* g = gw + lane * DDIM;
        const float* tr = tws + t * DDIM;
        float acc = 0.f;
        for (int d = 0; d < DDIM; d += 4) {
            acc = fmaf(tr[d], g[d], acc);
            acc = fmaf(tr[d + 1], g[d + 1], acc);
            acc = fmaf(tr[d + 2], g[d + 2], acc);
            acc = fmaf(tr[d + 3], g[d + 3], acc);
        }
        lg[lane] = acc + gb[lane];
    }
    __syncthreads();
    if (lane == 0) {
        float vals[KSEL];
        int idx[KSEL];
        for (int k = 0; k < KSEL; ++k) {
            float best = -1e30f;
            int bi = 0;
            for (int e = 0; e < NEXP; ++e) {
                float v = lg[e];
                if (v > best) { best = v; bi = e; }
            }
            vals[k] = best;
            idx[k] = bi;
            lg[bi] = -1e30f;
        }
        const float m = vals[0];
        float ex[KSEL];
        float se = 0.f;
        for (int k = 0; k < KSEL; ++k) { ex[k] = __expf(vals[k] - m); se += ex[k]; }
        const float inv = 1.0f / se;
        for (int k = 0; k < KSEL; ++k) {
            const int p = t * KSEL + k;
            ew[p] = ex[k] * inv;
            pexp[p] = idx[k];
            const int slot = atomicAdd(&counts[idx[k]], 1);
            list[idx[k] * NTOK + slot] = p;
        }
    }
}

// grid (5, 32, 32): x = col tile (256 cols of 1280), y = expert, z = rc*8 + tokenchunk
__global__ __launch_bounds__(64) void k_ffn1(const float* __restrict__ tws,
                                             const float* __restrict__ w1,
                                             float* __restrict__ hpart,
                                             const int* __restrict__ counts,
                                             const int* __restrict__ list) {
    const int e = blockIdx.y;
    const int rc = blockIdx.z >> 3;
    const int tc = blockIdx.z & 7;
    const int cnt = counts[e];
    const int c0 = tc * CHUNK;
    if (c0 >= cnt) return;
    const int col0 = blockIdx.x * 256 + threadIdx.x * 4;
    const int d0 = rc * RLEN;

    __shared__ float tl[CHUNK][RLEN];
    int pid[CHUNK];
#pragma unroll
    for (int s = 0; s < CHUNK; ++s) {
        int ii = c0 + s;
        ii = (ii < cnt) ? ii : c0;  // pad with first slot (identical math, same-value store)
        pid[s] = list[e * NTOK + ii];
    }
    for (int s = 0; s < CHUNK; ++s) {
        const int tok = pid[s] >> 2;
        for (int d = threadIdx.x; d < RLEN; d += 64)
            tl[s][d] = tws[tok * DDIM + d0 + d];
    }
    __syncthreads();

    const float* w1e = w1 + (size_t)e * DDIM * TWO_I;
    float acc[CHUNK][4];
#pragma unroll
    for (int s = 0; s < CHUNK; ++s)
#pragma unroll
        for (int c = 0; c < 4; ++c) acc[s][c] = 0.f;

#pragma unroll 4
    for (int dd = 0; dd < RLEN; ++dd) {
        const float4 w = *reinterpret_cast<const float4*>(&w1e[(size_t)(d0 + dd) * TWO_I + col0]);
#pragma unroll
        for (int s = 0; s < CHUNK; ++s) {
            const float tv = tl[s][dd];
            acc[s][0] = fmaf(tv, w.x, acc[s][0]);
            acc[s][1] = fmaf(tv, w.y, acc[s][1]);
            acc[s][2] = fmaf(tv, w.z, acc[s][2]);
            acc[s][3] = fmaf(tv, w.w, acc[s][3]);
        }
    }

#pragma unroll
    for (int s = 0; s < CHUNK; ++s) {
        float4 v = make_float4(acc[s][0], acc[s][1], acc[s][2], acc[s][3]);
        *reinterpret_cast<float4*>(&hpart[((size_t)rc * NPAIR + pid[s]) * TWO_I + col0]) = v;
    }
}

// grid (256) x 256: reduce rc partials, add bias, activation -> hact
__global__ void k_reduce1(const float* __restrict__ hpart, const float* __restrict__ b1,
                          const int* __restrict__ pexp, float* __restrict__ hact) {
    const int p = blockIdx.x;
    const int e = pexp[p];
    for (int i = threadIdx.x; i < IDIM; i += 256) {
        float g = 0.f, l = 0.f;
#pragma unroll
        for (int rc = 0; rc < RC; ++rc) {
            g += hpart[((size_t)rc * NPAIR + p) * TWO_I + i];
            l += hpart[((size_t)rc * NPAIR + p) * TWO_I + i + IDIM];
        }
        float hg = fminf(g + b1[e * TWO_I + i], LIMIT);
        float hl = l + b1[e * TWO_I + IDIM + i];
        hl = fminf(fmaxf(hl, -LIMIT), LIMIT);
        const float sig = 1.0f / (1.0f + __expf(-1.702f * hg));
        hact[(size_t)p * IDIM + i] = hg * sig * (hl + 1.0f);
    }
}

// grid (3, 32, 32): x = col tile (256 cols of 640, last partial), y = expert, z = rc*8+tc
__global__ __launch_bounds__(64) void k_ffn2(const float* __restrict__ hact,
                                             const float* __restrict__ w2,
                                             float* __restrict__ hpart2,
                                             const int* __restrict__ counts,
                                             const int* __restrict__ list) {
    const int e = blockIdx.y;
    const int rc = blockIdx.z >> 3;
    const int tc = blockIdx.z & 7;
    const int cnt = counts[e];
    const int c0 = tc * CHUNK;
    if (c0 >= cnt) return;
    const int col0 = blockIdx.x * 256 + threadIdx.x * 4;
    const bool colok = (col0 < DDIM);
    const int i0 = rc * RLEN;

    __shared__ float hl[CHUNK][RLEN];
    int pid[CHUNK];
#pragma unroll
    for (int s = 0; s < CHUNK; ++s) {
        int ii = c0 + s;
        ii = (ii < cnt) ? ii : c0;
        pid[s] = list[e * NTOK + ii];
    }
    for (int s = 0; s < CHUNK; ++s) {
        for (int i = threadIdx.x; i < RLEN; i += 64)
            hl[s][i] = hact[(size_t)pid[s] * IDIM + i0 + i];
    }
    __syncthreads();
    if (!colok) return;

    const float* w2e = w2 + (size_t)e * IDIM * DDIM;
    float acc[CHUNK][4];
#pragma unroll
    for (int s = 0; s < CHUNK; ++s)
#pragma unroll
        for (int c = 0; c < 4; ++c) acc[s][c] = 0.f;

#pragma unroll 4
    for (int ii = 0; ii < RLEN; ++ii) {
        const float4 w = *reinterpret_cast<const float4*>(&w2e[(size_t)(i0 + ii) * DDIM + col0]);
#pragma unroll
        for (int s = 0; s < CHUNK; ++s) {
            const float hv = hl[s][ii];
            acc[s][0] = fmaf(hv, w.x, acc[s][0]);
            acc[s][1] = fmaf(hv, w.y, acc[s][1]);
            acc[s][2] = fmaf(hv, w.z, acc[s][2]);
            acc[s][3] = fmaf(hv, w.w, acc[s][3]);
        }
    }

#pragma unroll
    for (int s = 0; s < CHUNK; ++s) {
        float4 v = make_float4(acc[s][0], acc[s][1], acc[s][2], acc[s][3]);
        *reinterpret_cast<float4*>(&hpart2[((size_t)rc * NPAIR + pid[s]) * DDIM + col0]) = v;
    }
}

// grid (64) x 256: reduce rc partials of ffn2, add bias, weight by ew, sum k, residual
__global__ void k_final(const float* __restrict__ x, const float* __restrict__ hpart2,
                        const float* __restrict__ b2, const float* __restrict__ ew,
                        const int* __restrict__ pexp, float* __restrict__ out) {
    const int t = blockIdx.x;
    for (int d = threadIdx.x; d < DDIM; d += 256) {
        float v = x[d * NTOK + t];
#pragma unroll
        for (int k = 0; k < KSEL; ++k) {
            const int p = t * KSEL + k;
            const int e = pexp[p];
            float s = 0.f;
#pragma unroll
            for (int rc = 0; rc < RC; ++rc)
                s += hpart2[((size_t)rc * NPAIR + p) * DDIM + d];
            v += (s + b2[e * DDIM + d]) * ew[p];
        }
        out[d * NTOK + t] = v;
    }
}

extern "C" void kernel_launch(void* const* d_in, const int* in_sizes, int n_in,
                              void* d_out, int out_size, void* d_ws, size_t ws_size,
                              hipStream_t stream) {
    const float* x  = (const float*)d_in[0];
    const float* nw = (const float*)d_in[1];
    const float* gw = (const float*)d_in[2];
    const float* gb = (const float*)d_in[3];
    const float* w1 = (const float*)d_in[4];
    const float* b1 = (const float*)d_in[5];
    const float* w2 = (const float*)d_in[6];
    const float* b2 = (const float*)d_in[7];
    float* out = (float*)d_out;

    float* ws    = (float*)d_ws;
    float* tws   = ws;                    // 40960
    float* hact  = ws + 40960;            // 163840
    float* hpart = ws + 204800;           // 1310720 (ffn1), reused for ffn2
    float* ew    = ws + 1515520;          // 256
    int* counts  = (int*)(ws + 1515776);  // 32
    int* list    = (int*)(ws + 1515808);  // 2048
    int* pexp    = (int*)(ws + 1517856);  // 256

    hipLaunchKernelGGL(k_rmsnorm, dim3(NTOK), dim3(256), 0, stream, x, nw, tws, counts);
    hipLaunchKernelGGL(k_router, dim3(NTOK), dim3(64), 0, stream, tws, gw, gb, ew, counts, list, pexp);
    hipLaunchKernelGGL(k_ffn1, dim3(5, NEXP, RC * 8), dim3(64), 0, stream, tws, w1, hpart, counts, list);
    hipLaunchKernelGGL(k_reduce1, dim3(NPAIR), dim3(256), 0, stream, hpart, b1, pexp, hact);
    hipLaunchKernelGGL(k_ffn2, dim3(3, NEXP, RC * 8), dim3(64), 0, stream, hact, w2, hpart, counts, list);
    hipLaunchKernelGGL(k_final, dim3(NTOK), dim3(256), 0, stream, x, hpart, b2, ew, pexp, out);
}

// Round 3
// 80.700 us; speedup vs baseline: 2.1032x; 1.5757x over previous
//
#include <hip/hip_runtime.h>
#include <math.h>

#define DDIM 640
#define IDIM 640
#define TWO_I 1280
#define KSEL 4
#define NEXP 32
#define NTOK 64
#define NPAIR 256
#define EPSV 1e-5f
#define LIMIT 7.0f
#define CHUNK 8
#define RC 8          // row chunks along the reduction dim
#define RLEN 80       // rows per chunk (640/8)

// ws layout (float elements):
//  tws    : [64][640]            @ 0         (40960)
//  hact   : [256][640]           @ 40960     (163840)
//  hpart  : [8][256][1280]       @ 204800    (2621440)  (ffn1 partials; reused as
//                                                        [8][256][640] for ffn2)
//  ew     : [256]                @ 2826240
//  counts : [32] (int)           @ 2826496
//  list   : [32][64] (int)       @ 2826528
//  pexp   : [256] (int)          @ 2828576
// total ~2828832 floats = ~11.3 MB

__global__ void k_rmsnorm(const float* __restrict__ x, const float* __restrict__ nw,
                          float* __restrict__ tws, int* __restrict__ counts) {
    const int t = blockIdx.x;
    const int tid = threadIdx.x;
    if (blockIdx.x == 0 && tid < NEXP) counts[tid] = 0;
    __shared__ float red[256];
    float s = 0.f;
    for (int d = tid; d < DDIM; d += 256) {
        float v = x[d * NTOK + t];
        s += v * v;
    }
    red[tid] = s;
    __syncthreads();
    for (int off = 128; off > 0; off >>= 1) {
        if (tid < off) red[tid] += red[tid + off];
        __syncthreads();
    }
    const float rs = 1.0f / sqrtf(red[0] * (1.0f / DDIM) + EPSV);
    for (int d = tid; d < DDIM; d += 256) {
        tws[t * DDIM + d] = x[d * NTOK + t] * rs * nw[d];
    }
}

__global__ void k_router(const float* __restrict__ tws, const float* __restrict__ gw,
                         const float* __restrict__ gb, float* __restrict__ ew,
                         int* __restrict__ counts, int* __restrict__ list,
                         int* __restrict__ pexp) {
    const int t = blockIdx.x;
    const int lane = threadIdx.x;
    __shared__ float lg[NEXP];
    if (lane < NEXP) {
        const float* g = gw + lane * DDIM;
        const float* tr = tws + t * DDIM;
        float acc = 0.f;
        for (int d = 0; d < DDIM; d += 4) {
            acc = fmaf(tr[d], g[d], acc);
            acc = fmaf(tr[d + 1], g[d + 1], acc);
            acc = fmaf(tr[d + 2], g[d + 2], acc);
            acc = fmaf(tr[d + 3], g[d + 3], acc);
        }
        lg[lane] = acc + gb[lane];
    }
    __syncthreads();
    if (lane == 0) {
        float vals[KSEL];
        int idx[KSEL];
        for (int k = 0; k < KSEL; ++k) {
            float best = -1e30f;
            int bi = 0;
            for (int e = 0; e < NEXP; ++e) {
                float v = lg[e];
                if (v > best) { best = v; bi = e; }
            }
            vals[k] = best;
            idx[k] = bi;
            lg[bi] = -1e30f;
        }
        const float m = vals[0];
        float ex[KSEL];
        float se = 0.f;
        for (int k = 0; k < KSEL; ++k) { ex[k] = __expf(vals[k] - m); se += ex[k]; }
        const float inv = 1.0f / se;
        for (int k = 0; k < KSEL; ++k) {
            const int p = t * KSEL + k;
            ew[p] = ex[k] * inv;
            pexp[p] = idx[k];
            const int slot = atomicAdd(&counts[idx[k]], 1);
            list[idx[k] * NTOK + slot] = p;
        }
    }
}

// grid (5, 32, RC*8): x = col tile (256 of 1280 cols, lane owns 4), y = expert,
// z = rc*8 + tokenchunk. One wave per block; deep-unrolled float4 weight loads.
__global__ __launch_bounds__(64) void k_ffn1(const float* __restrict__ tws,
                                             const float* __restrict__ w1,
                                             float* __restrict__ hpart,
                                             const int* __restrict__ counts,
                                             const int* __restrict__ list) {
    const int e = blockIdx.y;
    const int rc = blockIdx.z >> 3;
    const int tc = blockIdx.z & 7;
    const int cnt = counts[e];
    const int c0 = tc * CHUNK;
    if (c0 >= cnt) return;
    const int col0 = blockIdx.x * 256 + threadIdx.x * 4;
    const int d0 = rc * RLEN;

    __shared__ float tl[CHUNK][RLEN];
    int pid[CHUNK];
#pragma unroll
    for (int s = 0; s < CHUNK; ++s) {
        int ii = c0 + s;
        ii = (ii < cnt) ? ii : c0;  // pad with first slot (identical math, same-value store)
        pid[s] = list[e * NTOK + ii];
    }
    for (int s = 0; s < CHUNK; ++s) {
        const int tok = pid[s] >> 2;
        for (int d = threadIdx.x; d < RLEN; d += 64)
            tl[s][d] = tws[tok * DDIM + d0 + d];
    }
    __syncthreads();

    const float* wp = w1 + (size_t)e * DDIM * TWO_I + (size_t)d0 * TWO_I + col0;
    float acc[CHUNK][4];
#pragma unroll
    for (int s = 0; s < CHUNK; ++s)
#pragma unroll
        for (int c = 0; c < 4; ++c) acc[s][c] = 0.f;

    for (int dd = 0; dd < RLEN; dd += 8) {
        float4 w[8];
#pragma unroll
        for (int u = 0; u < 8; ++u)
            w[u] = *reinterpret_cast<const float4*>(wp + (size_t)(dd + u) * TWO_I);
#pragma unroll
        for (int u = 0; u < 8; ++u) {
#pragma unroll
            for (int s = 0; s < CHUNK; ++s) {
                const float tv = tl[s][dd + u];
                acc[s][0] = fmaf(tv, w[u].x, acc[s][0]);
                acc[s][1] = fmaf(tv, w[u].y, acc[s][1]);
                acc[s][2] = fmaf(tv, w[u].z, acc[s][2]);
                acc[s][3] = fmaf(tv, w[u].w, acc[s][3]);
            }
        }
    }

#pragma unroll
    for (int s = 0; s < CHUNK; ++s) {
        float4 v = make_float4(acc[s][0], acc[s][1], acc[s][2], acc[s][3]);
        *reinterpret_cast<float4*>(&hpart[((size_t)rc * NPAIR + pid[s]) * TWO_I + col0]) = v;
    }
}

// grid (256) x 256: reduce rc partials, add bias, activation -> hact
__global__ void k_reduce1(const float* __restrict__ hpart, const float* __restrict__ b1,
                          const int* __restrict__ pexp, float* __restrict__ hact) {
    const int p = blockIdx.x;
    const int e = pexp[p];
    for (int i = threadIdx.x; i < IDIM; i += 256) {
        float g = 0.f, l = 0.f;
#pragma unroll
        for (int rc = 0; rc < RC; ++rc) {
            g += hpart[((size_t)rc * NPAIR + p) * TWO_I + i];
            l += hpart[((size_t)rc * NPAIR + p) * TWO_I + i + IDIM];
        }
        float hg = fminf(g + b1[e * TWO_I + i], LIMIT);
        float hl = l + b1[e * TWO_I + IDIM + i];
        hl = fminf(fmaxf(hl, -LIMIT), LIMIT);
        const float sig = 1.0f / (1.0f + __expf(-1.702f * hg));
        hact[(size_t)p * IDIM + i] = hg * sig * (hl + 1.0f);
    }
}

// grid (5, 32, RC*8): x = col tile (128 of 640 cols, lane owns 2), y = expert, z = rc*8+tc
__global__ __launch_bounds__(64) void k_ffn2(const float* __restrict__ hact,
                                             const float* __restrict__ w2,
                                             float* __restrict__ hpart2,
                                             const int* __restrict__ counts,
                                             const int* __restrict__ list) {
    const int e = blockIdx.y;
    const int rc = blockIdx.z >> 3;
    const int tc = blockIdx.z & 7;
    const int cnt = counts[e];
    const int c0 = tc * CHUNK;
    if (c0 >= cnt) return;
    const int col0 = blockIdx.x * 128 + threadIdx.x * 2;
    const int i0 = rc * RLEN;

    __shared__ float hl[CHUNK][RLEN];
    int pid[CHUNK];
#pragma unroll
    for (int s = 0; s < CHUNK; ++s) {
        int ii = c0 + s;
        ii = (ii < cnt) ? ii : c0;
        pid[s] = list[e * NTOK + ii];
    }
    for (int s = 0; s < CHUNK; ++s) {
        for (int i = threadIdx.x; i < RLEN; i += 64)
            hl[s][i] = hact[(size_t)pid[s] * IDIM + i0 + i];
    }
    __syncthreads();

    const float* wp = w2 + (size_t)e * IDIM * DDIM + (size_t)i0 * DDIM + col0;
    float acc[CHUNK][2];
#pragma unroll
    for (int s = 0; s < CHUNK; ++s) {
        acc[s][0] = 0.f;
        acc[s][1] = 0.f;
    }

    for (int ii = 0; ii < RLEN; ii += 8) {
        float2 w[8];
#pragma unroll
        for (int u = 0; u < 8; ++u)
            w[u] = *reinterpret_cast<const float2*>(wp + (size_t)(ii + u) * DDIM);
#pragma unroll
        for (int u = 0; u < 8; ++u) {
#pragma unroll
            for (int s = 0; s < CHUNK; ++s) {
                const float hv = hl[s][ii + u];
                acc[s][0] = fmaf(hv, w[u].x, acc[s][0]);
                acc[s][1] = fmaf(hv, w[u].y, acc[s][1]);
            }
        }
    }

#pragma unroll
    for (int s = 0; s < CHUNK; ++s) {
        float2 v = make_float2(acc[s][0], acc[s][1]);
        *reinterpret_cast<float2*>(&hpart2[((size_t)rc * NPAIR + pid[s]) * DDIM + col0]) = v;
    }
}

// grid (64) x 256: reduce rc partials of ffn2, add bias, weight by ew, sum k, residual
__global__ void k_final(const float* __restrict__ x, const float* __restrict__ hpart2,
                        const float* __restrict__ b2, const float* __restrict__ ew,
                        const int* __restrict__ pexp, float* __restrict__ out) {
    const int t = blockIdx.x;
    for (int d = threadIdx.x; d < DDIM; d += 256) {
        float v = x[d * NTOK + t];
#pragma unroll
        for (int k = 0; k < KSEL; ++k) {
            const int p = t * KSEL + k;
            const int e = pexp[p];
            float s = 0.f;
#pragma unroll
            for (int rc = 0; rc < RC; ++rc)
                s += hpart2[((size_t)rc * NPAIR + p) * DDIM + d];
            v += (s + b2[e * DDIM + d]) * ew[p];
        }
        out[d * NTOK + t] = v;
    }
}

extern "C" void kernel_launch(void* const* d_in, const int* in_sizes, int n_in,
                              void* d_out, int out_size, void* d_ws, size_t ws_size,
                              hipStream_t stream) {
    const float* x  = (const float*)d_in[0];
    const float* nw = (const float*)d_in[1];
    const float* gw = (const float*)d_in[2];
    const float* gb = (const float*)d_in[3];
    const float* w1 = (const float*)d_in[4];
    const float* b1 = (const float*)d_in[5];
    const float* w2 = (const float*)d_in[6];
    const float* b2 = (const float*)d_in[7];
    float* out = (float*)d_out;

    float* ws    = (float*)d_ws;
    float* tws   = ws;                    // 40960
    float* hact  = ws + 40960;            // 163840
    float* hpart = ws + 204800;           // 2621440 (ffn1), reused for ffn2
    float* ew    = ws + 2826240;          // 256
    int* counts  = (int*)(ws + 2826496);  // 32
    int* list    = (int*)(ws + 2826528);  // 2048
    int* pexp    = (int*)(ws + 2828576);  // 256

    hipLaunchKernelGGL(k_rmsnorm, dim3(NTOK), dim3(256), 0, stream, x, nw, tws, counts);
    hipLaunchKernelGGL(k_router, dim3(NTOK), dim3(64), 0, stream, tws, gw, gb, ew, counts, list, pexp);
    hipLaunchKernelGGL(k_ffn1, dim3(5, NEXP, RC * 8), dim3(64), 0, stream, tws, w1, hpart, counts, list);
    hipLaunchKernelGGL(k_reduce1, dim3(NPAIR), dim3(256), 0, stream, hpart, b1, pexp, hact);
    hipLaunchKernelGGL(k_ffn2, dim3(5, NEXP, RC * 8), dim3(64), 0, stream, hact, w2, hpart, counts, list);
    hipLaunchKernelGGL(k_final, dim3(NTOK), dim3(256), 0, stream, x, hpart, b2, ew, pexp, out);
}